// Round 23
// baseline (155.497 us; speedup 1.0000x reference)
//
#include <hip/hip_runtime.h>

// DeformConv fused pipeline, MI355X gfx950. Shapes: B=2, Ci=Co=256, H=W=96.
// R23 changes vs R22 (s_gemm 44.9us: 1 block/CU + barrier-per-chunk lockstep,
// MfmaUtil 17.7% vs 8us FLOP floor):
//  - s_gemm: BARRIER-FREE reg-staged GEMM. Waves load A/B fragments directly
//    L2->VGPR (same addresses the LDS path staged), double-buffered named
//    frag sets, no LDS staging -> 2 blocks/CU, independent wave progress.
//  - everything else identical to R22 (132.4us).

typedef unsigned short ushort_t;
typedef unsigned int uint_t;
typedef __attribute__((ext_vector_type(8))) short bf16x8;
typedef __attribute__((ext_vector_type(4))) float f32x4;
typedef __attribute__((ext_vector_type(2))) float f32x2v;   // natural 8B align

#define HH 96
#define WW 96
#define HWSZ 9216
#define CI 256
#define CO 256
#define NB 2
#define NPIX 18432
#define KTOT 2304

__device__ __forceinline__ uint_t f2bf(float f) {
  unsigned int u = __float_as_uint(f);
  u += 0x7fffu + ((u >> 16) & 1u);
  return u >> 16;
}
__device__ __forceinline__ float u2f(uint_t u) { return __uint_as_float(u); }
__device__ __forceinline__ float bflo(uint_t u) { return __uint_as_float(u << 16); }
__device__ __forceinline__ float bfhi(uint_t u) { return __uint_as_float(u & 0xffff0000u); }

__device__ __forceinline__ void gload16(const void* g, void* l) {
  __builtin_amdgcn_global_load_lds(
      (const __attribute__((address_space(1))) unsigned int*)g,
      (__attribute__((address_space(3))) unsigned int*)l, 16, 0, 0);
}

// ---------------- cvt_w9: w_dcn -> bf16 [kk>>3][m][kk&7] ----------------
__global__ void cvt_w9(const float* __restrict__ w, ushort_t* __restrict__ o) {
  int i = blockIdx.x * 256 + threadIdx.x;      // grid exact CO*KTOT
  int oo = i / KTOT;
  int kk = i - oo * KTOT;
  o[(kk >> 3) * 2048 + oo * 8 + (kk & 7)] = (ushort_t)f2bf(w[i]);
}

// ---------------- cvt_woff9: w_off -> bf16 [kk>>3][m32][kk&7], rows>=27 zero ----
__global__ void cvt_woff9(const float* __restrict__ w, ushort_t* __restrict__ o) {
  int i = blockIdx.x * 256 + threadIdx.x;      // grid exact 32*KTOT
  int m = i / KTOT;
  int kk = i - m * KTOT;
  float v = (m < 27) ? w[m * KTOT + kk] : 0.f;
  o[(kk >> 3) * 256 + m * 8 + (kk & 7)] = (ushort_t)f2bf(v);
}

// ---------------- off_gemm: om_part[part][27][NPIX], K-split halves ----------------
__global__ __launch_bounds__(512, 2) void off_gemm(
    const float* __restrict__ x, const ushort_t* __restrict__ w27r,
    float* __restrict__ om_part) {
  __shared__ __align__(16) ushort_t A27[2][2048];
  __shared__ __align__(16) ushort_t B64[4096];
  __shared__ uint2 tbl[9][64];                 // {abs idx (0 if invalid), mask}

  const int tid = threadIdx.x;
  const int lane = tid & 63, wid = tid >> 6;
  const int p0 = blockIdx.x * 64;
  const int part = blockIdx.y;                 // K half
  const int bimg = p0 / HWSZ;
  const int hw0 = p0 - bimg * HWSZ;
  const float* xb = x + (size_t)bimg * CI * HWSZ;

  for (int e = tid; e < 576; e += 512) {
    int k = e >> 6, px = e & 63;
    int hw = hw0 + px, h = hw / WW, w_ = hw - h * WW;
    int dy = k / 3 - 1, dx = k % 3 - 1;
    bool ok = (h + dy >= 0) && (h + dy < HH) && (w_ + dx >= 0) && (w_ + dx < WW);
    tbl[k][px] = make_uint2(ok ? (uint_t)(hw + dy * WW + dx) : 0u,
                            ok ? 0x3f800000u : 0u);
  }

  const int lg = lane >> 4, lm = lane & 15;
  const int wr = wid >> 2, wc = wid & 3;
  f32x4 acc = (f32x4){0.f, 0.f, 0.f, 0.f};

  int cj[8], kj[8];
#pragma unroll
  for (int j = 0; j < 8; ++j) {
    int kk = part * 1152 + wid * 8 + j;
    cj[j] = kk / 9;
    kj[j] = kk - 9 * cj[j];
  }
  __syncthreads();

  float rv0[8], rm0[8], rv1[8], rm1[8];
  const int k0 = part * 18;

#define OG_RAW(RV, RM)                                                        \
  { _Pragma("unroll") for (int j = 0; j < 8; ++j) {                           \
      uint2 e_ = tbl[kj[j]][lane];                                            \
      RV[j] = xb[cj[j] * HWSZ + (int)e_.x];                                   \
      RM[j] = u2f(e_.y);                                                      \
      kj[j] += 1; cj[j] += 7;                                                 \
      if (kj[j] == 9) { kj[j] = 0; cj[j] += 1; } } }
#define OG_GA(CH, BUF)                                                        \
  gload16(w27r + (size_t)(CH) * 2048 + (tid & 255) * 8, &A27[BUF][(wid & 3) * 512]);
#define OG_STEP(CUR, RVC, RMC, RVN, RMN, KO)                                  \
  {                                                                           \
    if ((KO) < 17) {                                                          \
      OG_RAW(RVN, RMN)                                                        \
      OG_GA(k0 + (KO) + 1, (CUR) ^ 1)                                         \
      asm volatile("s_waitcnt vmcnt(10)" ::: "memory");                       \
    } else {                                                                  \
      asm volatile("s_waitcnt vmcnt(1)" ::: "memory");                        \
    }                                                                         \
    __builtin_amdgcn_sched_barrier(0);                                        \
    {                                                                         \
      ushort_t sv_[8] __attribute__((aligned(16)));                           \
      _Pragma("unroll") for (int j = 0; j < 8; ++j)                           \
        sv_[j] = (ushort_t)f2bf(RVC[j] * RMC[j]);                             \
      *(uint4*)&B64[tid * 8] = *(const uint4*)sv_;                            \
    }                                                                         \
    if ((KO) < 17) asm volatile("s_waitcnt vmcnt(9) lgkmcnt(0)" ::: "memory"); \
    else           asm volatile("s_waitcnt vmcnt(0) lgkmcnt(0)" ::: "memory"); \
    __builtin_amdgcn_s_barrier();                                             \
    __builtin_amdgcn_sched_barrier(0);                                        \
    _Pragma("unroll") for (int s = 0; s < 2; ++s) {                           \
      bf16x8 af = *(const bf16x8*)&A27[CUR][((s * 4 + lg) * 32 + wr * 16 + lm) * 8]; \
      bf16x8 bfv = *(const bf16x8*)&B64[((s * 4 + lg) * 64 + wc * 16 + lm) * 8];     \
      acc = __builtin_amdgcn_mfma_f32_16x16x32_bf16(af, bfv, acc, 0, 0, 0);   \
    }                                                                         \
    asm volatile("s_waitcnt lgkmcnt(0)" ::: "memory");                        \
    __builtin_amdgcn_s_barrier();                                             \
    __builtin_amdgcn_sched_barrier(0);                                        \
  }

  OG_RAW(rv0, rm0)
  OG_GA(k0, 0)
  for (int ko2 = 0; ko2 < 9; ++ko2) {
    const int ko = ko2 * 2;
    OG_STEP(0, rv0, rm0, rv1, rm1, ko)
    OG_STEP(1, rv1, rm1, rv0, rm0, ko + 1)
  }
#undef OG_RAW
#undef OG_GA
#undef OG_STEP

  int row = wr * 16 + lg * 4;
  int col = p0 + wc * 16 + lm;
#pragma unroll
  for (int r = 0; r < 4; ++r)
    if (row + r < 27)
      om_part[((size_t)(part * 27 + row + r)) * NPIX + col] = acc[r];
}

// ---------------- prep: sum om halves -> row-pair offsets + folded weights ----------------
__global__ void prep_kernel(const float* __restrict__ om_part, const float* __restrict__ b_off,
                            uint_t* __restrict__ offs, float4* __restrict__ wts) {
  int n = blockIdx.x * 128 + threadIdx.x;      // grid 144 x 128
  float omv[27];
#pragma unroll
  for (int ch = 0; ch < 27; ++ch)
    omv[ch] = b_off[ch] + om_part[(size_t)ch * NPIX + n] +
              om_part[((size_t)(27 + ch)) * NPIX + n];
  int hw = n % HWSZ;
  int h = hw / WW, w = hw - h * WW;
#pragma unroll
  for (int k = 0; k < 9; ++k) {
    float dy = omv[2 * k], dx = omv[2 * k + 1];
    float mk = 1.f / (1.f + __expf(-omv[18 + k]));
    float py = dy + (float)(h - 1 + k / 3);
    float px = dx + (float)(w - 1 + k % 3);
    float y0f = floorf(py), x0f = floorf(px);
    int y0 = (int)y0f, x0 = (int)x0f;
    float wy1 = py - y0f, wx1 = px - x0f;
    float wy0 = 1.f - wy1, wx0 = 1.f - wx1;
    float vy0 = (y0 >= 0 && y0 <= HH - 1) ? 1.f : 0.f;
    float vy1 = (y0 + 1 >= 0 && y0 + 1 <= HH - 1) ? 1.f : 0.f;
    int yc0 = min(max(y0, 0), HH - 1), yc1 = min(max(y0 + 1, 0), HH - 1);
    int xa = min(max(x0, 0), WW - 2);
    float a_, b_;
    if (x0 >= 0 && x0 <= WW - 2)      { a_ = wx0; b_ = wx1; }
    else if (x0 == -1)                { a_ = wx1; b_ = 0.f; }
    else if (x0 == WW - 1)            { a_ = 0.f; b_ = wx0; }
    else                              { a_ = 0.f; b_ = 0.f; }
    float s0 = mk * vy0 * wy0, s1 = mk * vy1 * wy1;
    offs[(size_t)k * NPIX + n] = (uint_t)(yc0 * WW + xa) | ((uint_t)(yc1 * WW + xa) << 16);
    wts[(size_t)k * NPIX + n] = make_float4(a_ * s0, b_ * s0, a_ * s1, b_ * s1);
  }
}

// ---------------- sample8: S_g[kk>>3][n][kk&7] bf16, 8 channels/block ----------------
__global__ __launch_bounds__(512, 1) void sample8(
    const float* __restrict__ x, const uint_t* __restrict__ offs,
    const float4* __restrict__ wts, ushort_t* __restrict__ S_g) {
  __shared__ __align__(16) uint_t xqA[HWSZ * 2];   // ch0..3, 73,728 B
  __shared__ __align__(16) uint_t xqB[HWSZ * 2];   // ch4..7, 73,728 B
  const int tid = threadIdx.x;
  const int img = blockIdx.x >> 2;
  const int quarter = blockIdx.x & 3;
  const int by = blockIdx.y;                   // 0..31
  const int n0 = img * HWSZ + quarter * 2304;
  const int c8 = by * 8;

  {
    const float* s0 = x + ((size_t)(img * CI + c8)) * HWSZ;
#pragma unroll
    for (int i = 0; i < 9; ++i) {
      int col = i * 1024 + tid * 2;            // even, < 9216
      f32x2v c0 = *(const f32x2v*)(s0 + 0 * HWSZ + col);
      f32x2v c1 = *(const f32x2v*)(s0 + 1 * HWSZ + col);
      f32x2v c2 = *(const f32x2v*)(s0 + 2 * HWSZ + col);
      f32x2v c3 = *(const f32x2v*)(s0 + 3 * HWSZ + col);
      uint4 pkA;
      pkA.x = f2bf(c0[0]) | (f2bf(c1[0]) << 16);
      pkA.y = f2bf(c2[0]) | (f2bf(c3[0]) << 16);
      pkA.z = f2bf(c0[1]) | (f2bf(c1[1]) << 16);
      pkA.w = f2bf(c2[1]) | (f2bf(c3[1]) << 16);
      *(uint4*)&xqA[col * 2] = pkA;
      f32x2v c4 = *(const f32x2v*)(s0 + 4 * HWSZ + col);
      f32x2v c5 = *(const f32x2v*)(s0 + 5 * HWSZ + col);
      f32x2v c6 = *(const f32x2v*)(s0 + 6 * HWSZ + col);
      f32x2v c7 = *(const f32x2v*)(s0 + 7 * HWSZ + col);
      uint4 pkB;
      pkB.x = f2bf(c4[0]) | (f2bf(c5[0]) << 16);
      pkB.y = f2bf(c6[0]) | (f2bf(c7[0]) << 16);
      pkB.z = f2bf(c4[1]) | (f2bf(c5[1]) << 16);
      pkB.w = f2bf(c6[1]) | (f2bf(c7[1]) << 16);
      *(uint4*)&xqB[col * 2] = pkB;
    }
  }
  __syncthreads();

  for (int it = 0; it < 5; ++it) {
    if (it == 4 && tid >= 256) break;          // no barriers below; safe
    const int n = n0 + it * 512 + tid;
    uint_t ofr[9]; float4 wtr[9];
#pragma unroll
    for (int k = 0; k < 9; ++k) {
      ofr[k] = offs[(size_t)k * NPIX + n];
      wtr[k] = wts[(size_t)k * NPIX + n];
    }
    uint_t pkw[36];
#pragma unroll
    for (int i = 0; i < 36; ++i) pkw[i] = 0u;
#pragma unroll
    for (int k = 0; k < 9; ++k) {
      const int o0 = (int)(ofr[k] & 0xffffu);
      const int o1 = (int)(ofr[k] >> 16);
      const float4 wv = wtr[k];
      uint2 A00 = *(const uint2*)&xqA[o0 * 2];
      uint2 A01 = *(const uint2*)&xqA[o0 * 2 + 2];
      uint2 A10 = *(const uint2*)&xqA[o1 * 2];
      uint2 A11 = *(const uint2*)&xqA[o1 * 2 + 2];
      uint2 B00 = *(const uint2*)&xqB[o0 * 2];
      uint2 B01 = *(const uint2*)&xqB[o0 * 2 + 2];
      uint2 B10 = *(const uint2*)&xqB[o1 * 2];
      uint2 B11 = *(const uint2*)&xqB[o1 * 2 + 2];
      float v[8];
      v[0] = wv.x * bflo(A00.x) + wv.y * bflo(A01.x) + wv.z * bflo(A10.x) + wv.w * bflo(A11.x);
      v[1] = wv.x * bfhi(A00.x) + wv.y * bfhi(A01.x) + wv.z * bfhi(A10.x) + wv.w * bfhi(A11.x);
      v[2] = wv.x * bflo(A00.y) + wv.y * bflo(A01.y) + wv.z * bflo(A10.y) + wv.w * bflo(A11.y);
      v[3] = wv.x * bfhi(A00.y) + wv.y * bfhi(A01.y) + wv.z * bfhi(A10.y) + wv.w * bfhi(A11.y);
      v[4] = wv.x * bflo(B00.x) + wv.y * bflo(B01.x) + wv.z * bflo(B10.x) + wv.w * bflo(B11.x);
      v[5] = wv.x * bfhi(B00.x) + wv.y * bfhi(B01.x) + wv.z * bfhi(B10.x) + wv.w * bfhi(B11.x);
      v[6] = wv.x * bflo(B00.y) + wv.y * bflo(B01.y) + wv.z * bflo(B10.y) + wv.w * bflo(B11.y);
      v[7] = wv.x * bfhi(B00.y) + wv.y * bfhi(B01.y) + wv.z * bfhi(B10.y) + wv.w * bfhi(B11.y);
#pragma unroll
      for (int c = 0; c < 8; ++c) {
        const int q = c * 9 + k;               // static
        pkw[q >> 1] |= f2bf(v[c]) << ((q & 1) * 16);
      }
    }
#pragma unroll
    for (int g = 0; g < 9; ++g) {
      uint4 st = make_uint4(pkw[4 * g], pkw[4 * g + 1], pkw[4 * g + 2], pkw[4 * g + 3]);
      *(uint4*)&S_g[((size_t)(9 * by + g) * NPIX + n) * 8] = st;
    }
  }
}

// ---------------- s_gemm: out = W9 * S + b_dcn ; BN partials fused ----------------
// BM=128, BN=128, BK=32, 72 chunks, grid (144,2). BARRIER-FREE: fragments
// loaded L2->VGPR directly, double-buffered named sets, no LDS staging.
__global__ __launch_bounds__(512, 2) void s_gemm(
    const ushort_t* __restrict__ w9r, const ushort_t* __restrict__ S_g,
    const float* __restrict__ b_dcn, float* __restrict__ out,
    float2* __restrict__ bnp2) {
  __shared__ float red[512];                   // BN reduction only (2 KB)

  const int tid = threadIdx.x;
  const int lane = tid & 63, wid = tid >> 6;
  const int p0 = blockIdx.x * 128;             // 144 n-tiles
  const int m0 = blockIdx.y * 128;             // channel half
  const int bimg = p0 / HWSZ;
  const int hw0 = p0 - bimg * HWSZ;
  const int lg = lane >> 4, lm = lane & 15;
  const int wr = wid >> 1, wc = wid & 1;       // wave tile rows wr*32, cols wc*64

  const ushort_t* pa = w9r + ((size_t)lg * 256 + m0 + wr * 32 + lm) * 8;
  const ushort_t* ps = S_g + ((size_t)lg * NPIX + p0 + wc * 64 + lm) * 8;
  const size_t SSTR = (size_t)4 * NPIX * 8;    // S chunk stride (elements)

  f32x4 acc[2][4];
#pragma unroll
  for (int i = 0; i < 2; ++i)
#pragma unroll
    for (int j = 0; j < 4; ++j) acc[i][j] = (f32x4){0.f, 0.f, 0.f, 0.f};

#define SG_LOAD(CH, A0_, A1_, B0_, B1_, B2_, B3_)                             \
  {                                                                           \
    const ushort_t* pa_ = pa + (size_t)(CH) * 8192;                           \
    A0_ = *(const bf16x8*)(pa_);                                              \
    A1_ = *(const bf16x8*)(pa_ + 128);                                        \
    const ushort_t* ps_ = ps + (size_t)(CH) * SSTR;                           \
    B0_ = *(const bf16x8*)(ps_);                                              \
    B1_ = *(const bf16x8*)(ps_ + 128);                                        \
    B2_ = *(const bf16x8*)(ps_ + 256);                                        \
    B3_ = *(const bf16x8*)(ps_ + 384);                                        \
  }
#define SG_MM(A0_, A1_, B0_, B1_, B2_, B3_)                                   \
  {                                                                           \
    acc[0][0] = __builtin_amdgcn_mfma_f32_16x16x32_bf16(A0_, B0_, acc[0][0], 0, 0, 0); \
    acc[1][0] = __builtin_amdgcn_mfma_f32_16x16x32_bf16(A1_, B0_, acc[1][0], 0, 0, 0); \
    acc[0][1] = __builtin_amdgcn_mfma_f32_16x16x32_bf16(A0_, B1_, acc[0][1], 0, 0, 0); \
    acc[1][1] = __builtin_amdgcn_mfma_f32_16x16x32_bf16(A1_, B1_, acc[1][1], 0, 0, 0); \
    acc[0][2] = __builtin_amdgcn_mfma_f32_16x16x32_bf16(A0_, B2_, acc[0][2], 0, 0, 0); \
    acc[1][2] = __builtin_amdgcn_mfma_f32_16x16x32_bf16(A1_, B2_, acc[1][2], 0, 0, 0); \
    acc[0][3] = __builtin_amdgcn_mfma_f32_16x16x32_bf16(A0_, B3_, acc[0][3], 0, 0, 0); \
    acc[1][3] = __builtin_amdgcn_mfma_f32_16x16x32_bf16(A1_, B3_, acc[1][3], 0, 0, 0); \
  }

  bf16x8 xa0, xa1, xb0, xb1, xb2, xb3;         // set X
  bf16x8 ya0, ya1, yb0, yb1, yb2, yb3;         // set Y
  SG_LOAD(0, xa0, xa1, xb0, xb1, xb2, xb3)
  SG_LOAD(1, ya0, ya1, yb0, yb1, yb2, yb3)
  for (int ko = 0; ko < 68; ko += 2) {
    SG_MM(xa0, xa1, xb0, xb1, xb2, xb3)
    SG_LOAD(ko + 2, xa0, xa1, xb0, xb1, xb2, xb3)
    SG_MM(ya0, ya1, yb0, yb1, yb2, yb3)
    SG_LOAD(ko + 3, ya0, ya1, yb0, yb1, yb2, yb3)
  }
  SG_MM(xa0, xa1, xb0, xb1, xb2, xb3)          // chunk 68
  SG_LOAD(70, xa0, xa1, xb0, xb1, xb2, xb3)
  SG_MM(ya0, ya1, yb0, yb1, yb2, yb3)          // chunk 69
  SG_LOAD(71, ya0, ya1, yb0, yb1, yb2, yb3)
  SG_MM(xa0, xa1, xb0, xb1, xb2, xb3)          // chunk 70
  SG_MM(ya0, ya1, yb0, yb1, yb2, yb3)          // chunk 71
#undef SG_LOAD
#undef SG_MM

  // ---- epilogue: store out + BN partial stats ----
  float bsum[8], bsq[8];
#pragma unroll
  for (int mi = 0; mi < 2; ++mi) {
#pragma unroll
    for (int r = 0; r < 4; ++r) {
      int o = m0 + wr * 32 + mi * 16 + lg * 4 + r;
      float b = b_dcn[o];
      float s = 0.f, q = 0.f;
#pragma unroll
      for (int ni = 0; ni < 4; ++ni) {
        float v = acc[mi][ni][r] + b;
        out[((size_t)(bimg * CO + o)) * HWSZ + hw0 + wc * 64 + ni * 16 + lm] = v;
        s += v; q += v * v;
      }
      bsum[mi * 4 + r] = s;
      bsq[mi * 4 + r] = q;
    }
  }
#pragma unroll
  for (int d = 1; d < 16; d <<= 1) {
#pragma unroll
    for (int i = 0; i < 8; ++i) {
      bsum[i] += __shfl_xor(bsum[i], d);
      bsq[i] += __shfl_xor(bsq[i], d);
    }
  }
  if (lm == 0) {
#pragma unroll
    for (int i = 0; i < 8; ++i) {
      int ol = wr * 32 + (i >> 2) * 16 + lg * 4 + (i & 3);   // 0..127
      red[ol * 2 + wc] = bsum[i];
      red[256 + ol * 2 + wc] = bsq[i];
    }
  }
  __syncthreads();
  if (tid < 128) {
    float s = red[tid * 2] + red[tid * 2 + 1];
    float q = red[256 + tid * 2] + red[256 + tid * 2 + 1];
    bnp2[(size_t)(m0 + tid) * 144 + blockIdx.x] = make_float2(s, q);
  }
}

// ---------------- BN finalize: 256 blocks x 64 thr ----------------
__global__ __launch_bounds__(64) void bn_finl(const float2* __restrict__ bnp2,
                                              const float* __restrict__ gamma,
                                              const float* __restrict__ beta,
                                              float* __restrict__ ss) {
  int o = blockIdx.x, t = threadIdx.x;
  float s = 0.f, q = 0.f;
  for (int j = t; j < 144; j += 64) {
    float2 p = bnp2[(size_t)o * 144 + j];
    s += p.x; q += p.y;
  }
#pragma unroll
  for (int d = 32; d > 0; d >>= 1) {
    s += __shfl_xor(s, d);
    q += __shfl_xor(q, d);
  }
  if (t == 0) {
    float mean = s * (1.f / (float)NPIX);
    float var = q * (1.f / (float)NPIX) - mean * mean;
    float rstd = rsqrtf(var + 1e-5f);
    float sc = rstd * gamma[o];
    ss[o] = sc;
    ss[CO + o] = beta[o] - mean * sc;
  }
}

// ---------------- BN apply + ReLU ----------------
__global__ void bn_apply(float* __restrict__ out, const float* __restrict__ ss) {
  int i = blockIdx.x * 256 + threadIdx.x;
  float4 v = ((float4*)out)[i];
  int o = (i / (HWSZ / 4)) & 255;
  float sc = ss[o], sh = ss[CO + o];
  v.x = fmaxf(v.x * sc + sh, 0.f);
  v.y = fmaxf(v.y * sc + sh, 0.f);
  v.z = fmaxf(v.z * sc + sh, 0.f);
  v.w = fmaxf(v.w * sc + sh, 0.f);
  ((float4*)out)[i] = v;
}

extern "C" void kernel_launch(void* const* d_in, const int* in_sizes, int n_in,
                              void* d_out, int out_size, void* d_ws, size_t ws_size,
                              hipStream_t stream) {
  const float* x = (const float*)d_in[0];
  const float* w_off = (const float*)d_in[1];
  const float* b_off = (const float*)d_in[2];
  const float* w_dcn = (const float*)d_in[3];
  const float* b_dcn = (const float*)d_in[4];
  const float* gamma = (const float*)d_in[5];
  const float* beta = (const float*)d_in[6];
  float* out = (float*)d_out;

  char* ws = (char*)d_ws;

  size_t base = 84934656;                      // S_g occupies [0, base)
  ushort_t* S_g   = (ushort_t*)(ws);
  float*    om    = (float*)(ws + base);                    // 2*27*NPIX*4 = 3,981,312
  float2*   bnp2  = (float2*)(ws + base);                   // aliases om (dead after prep)
  uint_t*   offs  = (uint_t*)(ws + base + 3981312);         //   663,552
  float4*   wts   = (float4*)(ws + base + 4644864);         // 2,654,208
  ushort_t* w9r   = (ushort_t*)(ws + base + 7299072);       // 1,179,648
  ushort_t* w27r  = (ushort_t*)(ws + base + 8478720);       //   147,456
  float*    ss    = (float*)(ws + base + 8626176);          //     2,048

  cvt_w9<<<(CO * KTOT) / 256, 256, 0, stream>>>(w_dcn, w9r);
  cvt_woff9<<<(32 * KTOT) / 256, 256, 0, stream>>>(w_off, w27r);
  off_gemm<<<dim3(NPIX / 64, 2), 512, 0, stream>>>(x, w27r, om);
  prep_kernel<<<NPIX / 128, 128, 0, stream>>>(om, b_off, offs, wts);
  sample8<<<dim3(8, 32), 512, 0, stream>>>(x, offs, wts, S_g);
  s_gemm<<<dim3(NPIX / 128, 2), 512, 0, stream>>>(w9r, S_g, b_dcn, out, bnp2);
  bn_finl<<<CO, 64, 0, stream>>>(bnp2, gamma, beta, ss);
  bn_apply<<<(out_size / 4) / 256, 256, 0, stream>>>(out, ss);
}

// Round 24
// 132.262 us; speedup vs baseline: 1.1757x; 1.1757x over previous
//
#include <hip/hip_runtime.h>

// DeformConv fused pipeline, MI355X gfx950. Shapes: B=2, Ci=Co=256, H=W=96.
// R24 changes vs R23 (reg-staged s_gemm regressed 45->68: VGPR=56 shows the
// compiler serialized the frag loads again; revert to R22's LDS ring):
//  - s_gemm: R22 4-slot ring but BN=64 -> grid (288,2)=576 blocks, ring 48KB
//    -> 2.25 blocks/CU RESIDENT (R22's real limiter was grid 288 = 1/CU).
//  - everything else identical to R22 (132.4us best).

typedef unsigned short ushort_t;
typedef unsigned int uint_t;
typedef __attribute__((ext_vector_type(8))) short bf16x8;
typedef __attribute__((ext_vector_type(4))) float f32x4;
typedef __attribute__((ext_vector_type(2))) float f32x2v;   // natural 8B align

#define HH 96
#define WW 96
#define HWSZ 9216
#define CI 256
#define CO 256
#define NB 2
#define NPIX 18432
#define KTOT 2304

__device__ __forceinline__ uint_t f2bf(float f) {
  unsigned int u = __float_as_uint(f);
  u += 0x7fffu + ((u >> 16) & 1u);
  return u >> 16;
}
__device__ __forceinline__ float u2f(uint_t u) { return __uint_as_float(u); }
__device__ __forceinline__ float bflo(uint_t u) { return __uint_as_float(u << 16); }
__device__ __forceinline__ float bfhi(uint_t u) { return __uint_as_float(u & 0xffff0000u); }

__device__ __forceinline__ void gload16(const void* g, void* l) {
  __builtin_amdgcn_global_load_lds(
      (const __attribute__((address_space(1))) unsigned int*)g,
      (__attribute__((address_space(3))) unsigned int*)l, 16, 0, 0);
}

// ---------------- cvt_w9: w_dcn -> bf16 [kk>>3][m][kk&7] ----------------
__global__ void cvt_w9(const float* __restrict__ w, ushort_t* __restrict__ o) {
  int i = blockIdx.x * 256 + threadIdx.x;      // grid exact CO*KTOT
  int oo = i / KTOT;
  int kk = i - oo * KTOT;
  o[(kk >> 3) * 2048 + oo * 8 + (kk & 7)] = (ushort_t)f2bf(w[i]);
}

// ---------------- cvt_woff9: w_off -> bf16 [kk>>3][m32][kk&7], rows>=27 zero ----
__global__ void cvt_woff9(const float* __restrict__ w, ushort_t* __restrict__ o) {
  int i = blockIdx.x * 256 + threadIdx.x;      // grid exact 32*KTOT
  int m = i / KTOT;
  int kk = i - m * KTOT;
  float v = (m < 27) ? w[m * KTOT + kk] : 0.f;
  o[(kk >> 3) * 256 + m * 8 + (kk & 7)] = (ushort_t)f2bf(v);
}

// ---------------- off_gemm: om_part[part][27][NPIX], K-split halves ----------------
__global__ __launch_bounds__(512, 2) void off_gemm(
    const float* __restrict__ x, const ushort_t* __restrict__ w27r,
    float* __restrict__ om_part) {
  __shared__ __align__(16) ushort_t A27[2][2048];
  __shared__ __align__(16) ushort_t B64[4096];
  __shared__ uint2 tbl[9][64];                 // {abs idx (0 if invalid), mask}

  const int tid = threadIdx.x;
  const int lane = tid & 63, wid = tid >> 6;
  const int p0 = blockIdx.x * 64;
  const int part = blockIdx.y;                 // K half
  const int bimg = p0 / HWSZ;
  const int hw0 = p0 - bimg * HWSZ;
  const float* xb = x + (size_t)bimg * CI * HWSZ;

  for (int e = tid; e < 576; e += 512) {
    int k = e >> 6, px = e & 63;
    int hw = hw0 + px, h = hw / WW, w_ = hw - h * WW;
    int dy = k / 3 - 1, dx = k % 3 - 1;
    bool ok = (h + dy >= 0) && (h + dy < HH) && (w_ + dx >= 0) && (w_ + dx < WW);
    tbl[k][px] = make_uint2(ok ? (uint_t)(hw + dy * WW + dx) : 0u,
                            ok ? 0x3f800000u : 0u);
  }

  const int lg = lane >> 4, lm = lane & 15;
  const int wr = wid >> 2, wc = wid & 3;
  f32x4 acc = (f32x4){0.f, 0.f, 0.f, 0.f};

  int cj[8], kj[8];
#pragma unroll
  for (int j = 0; j < 8; ++j) {
    int kk = part * 1152 + wid * 8 + j;
    cj[j] = kk / 9;
    kj[j] = kk - 9 * cj[j];
  }
  __syncthreads();

  float rv0[8], rm0[8], rv1[8], rm1[8];
  const int k0 = part * 18;

#define OG_RAW(RV, RM)                                                        \
  { _Pragma("unroll") for (int j = 0; j < 8; ++j) {                           \
      uint2 e_ = tbl[kj[j]][lane];                                            \
      RV[j] = xb[cj[j] * HWSZ + (int)e_.x];                                   \
      RM[j] = u2f(e_.y);                                                      \
      kj[j] += 1; cj[j] += 7;                                                 \
      if (kj[j] == 9) { kj[j] = 0; cj[j] += 1; } } }
#define OG_GA(CH, BUF)                                                        \
  gload16(w27r + (size_t)(CH) * 2048 + (tid & 255) * 8, &A27[BUF][(wid & 3) * 512]);
#define OG_STEP(CUR, RVC, RMC, RVN, RMN, KO)                                  \
  {                                                                           \
    if ((KO) < 17) {                                                          \
      OG_RAW(RVN, RMN)                                                        \
      OG_GA(k0 + (KO) + 1, (CUR) ^ 1)                                         \
      asm volatile("s_waitcnt vmcnt(10)" ::: "memory");                       \
    } else {                                                                  \
      asm volatile("s_waitcnt vmcnt(1)" ::: "memory");                        \
    }                                                                         \
    __builtin_amdgcn_sched_barrier(0);                                        \
    {                                                                         \
      ushort_t sv_[8] __attribute__((aligned(16)));                           \
      _Pragma("unroll") for (int j = 0; j < 8; ++j)                           \
        sv_[j] = (ushort_t)f2bf(RVC[j] * RMC[j]);                             \
      *(uint4*)&B64[tid * 8] = *(const uint4*)sv_;                            \
    }                                                                         \
    if ((KO) < 17) asm volatile("s_waitcnt vmcnt(9) lgkmcnt(0)" ::: "memory"); \
    else           asm volatile("s_waitcnt vmcnt(0) lgkmcnt(0)" ::: "memory"); \
    __builtin_amdgcn_s_barrier();                                             \
    __builtin_amdgcn_sched_barrier(0);                                        \
    _Pragma("unroll") for (int s = 0; s < 2; ++s) {                           \
      bf16x8 af = *(const bf16x8*)&A27[CUR][((s * 4 + lg) * 32 + wr * 16 + lm) * 8]; \
      bf16x8 bfv = *(const bf16x8*)&B64[((s * 4 + lg) * 64 + wc * 16 + lm) * 8];     \
      acc = __builtin_amdgcn_mfma_f32_16x16x32_bf16(af, bfv, acc, 0, 0, 0);   \
    }                                                                         \
    asm volatile("s_waitcnt lgkmcnt(0)" ::: "memory");                        \
    __builtin_amdgcn_s_barrier();                                             \
    __builtin_amdgcn_sched_barrier(0);                                        \
  }

  OG_RAW(rv0, rm0)
  OG_GA(k0, 0)
  for (int ko2 = 0; ko2 < 9; ++ko2) {
    const int ko = ko2 * 2;
    OG_STEP(0, rv0, rm0, rv1, rm1, ko)
    OG_STEP(1, rv1, rm1, rv0, rm0, ko + 1)
  }
#undef OG_RAW
#undef OG_GA
#undef OG_STEP

  int row = wr * 16 + lg * 4;
  int col = p0 + wc * 16 + lm;
#pragma unroll
  for (int r = 0; r < 4; ++r)
    if (row + r < 27)
      om_part[((size_t)(part * 27 + row + r)) * NPIX + col] = acc[r];
}

// ---------------- prep: sum om halves -> row-pair offsets + folded weights ----------------
__global__ void prep_kernel(const float* __restrict__ om_part, const float* __restrict__ b_off,
                            uint_t* __restrict__ offs, float4* __restrict__ wts) {
  int n = blockIdx.x * 128 + threadIdx.x;      // grid 144 x 128
  float omv[27];
#pragma unroll
  for (int ch = 0; ch < 27; ++ch)
    omv[ch] = b_off[ch] + om_part[(size_t)ch * NPIX + n] +
              om_part[((size_t)(27 + ch)) * NPIX + n];
  int hw = n % HWSZ;
  int h = hw / WW, w = hw - h * WW;
#pragma unroll
  for (int k = 0; k < 9; ++k) {
    float dy = omv[2 * k], dx = omv[2 * k + 1];
    float mk = 1.f / (1.f + __expf(-omv[18 + k]));
    float py = dy + (float)(h - 1 + k / 3);
    float px = dx + (float)(w - 1 + k % 3);
    float y0f = floorf(py), x0f = floorf(px);
    int y0 = (int)y0f, x0 = (int)x0f;
    float wy1 = py - y0f, wx1 = px - x0f;
    float wy0 = 1.f - wy1, wx0 = 1.f - wx1;
    float vy0 = (y0 >= 0 && y0 <= HH - 1) ? 1.f : 0.f;
    float vy1 = (y0 + 1 >= 0 && y0 + 1 <= HH - 1) ? 1.f : 0.f;
    int yc0 = min(max(y0, 0), HH - 1), yc1 = min(max(y0 + 1, 0), HH - 1);
    int xa = min(max(x0, 0), WW - 2);
    float a_, b_;
    if (x0 >= 0 && x0 <= WW - 2)      { a_ = wx0; b_ = wx1; }
    else if (x0 == -1)                { a_ = wx1; b_ = 0.f; }
    else if (x0 == WW - 1)            { a_ = 0.f; b_ = wx0; }
    else                              { a_ = 0.f; b_ = 0.f; }
    float s0 = mk * vy0 * wy0, s1 = mk * vy1 * wy1;
    offs[(size_t)k * NPIX + n] = (uint_t)(yc0 * WW + xa) | ((uint_t)(yc1 * WW + xa) << 16);
    wts[(size_t)k * NPIX + n] = make_float4(a_ * s0, b_ * s0, a_ * s1, b_ * s1);
  }
}

// ---------------- sample8: S_g[kk>>3][n][kk&7] bf16, 8 channels/block ----------------
__global__ __launch_bounds__(512, 1) void sample8(
    const float* __restrict__ x, const uint_t* __restrict__ offs,
    const float4* __restrict__ wts, ushort_t* __restrict__ S_g) {
  __shared__ __align__(16) uint_t xqA[HWSZ * 2];   // ch0..3, 73,728 B
  __shared__ __align__(16) uint_t xqB[HWSZ * 2];   // ch4..7, 73,728 B
  const int tid = threadIdx.x;
  const int img = blockIdx.x >> 2;
  const int quarter = blockIdx.x & 3;
  const int by = blockIdx.y;                   // 0..31
  const int n0 = img * HWSZ + quarter * 2304;
  const int c8 = by * 8;

  {
    const float* s0 = x + ((size_t)(img * CI + c8)) * HWSZ;
#pragma unroll
    for (int i = 0; i < 9; ++i) {
      int col = i * 1024 + tid * 2;            // even, < 9216
      f32x2v c0 = *(const f32x2v*)(s0 + 0 * HWSZ + col);
      f32x2v c1 = *(const f32x2v*)(s0 + 1 * HWSZ + col);
      f32x2v c2 = *(const f32x2v*)(s0 + 2 * HWSZ + col);
      f32x2v c3 = *(const f32x2v*)(s0 + 3 * HWSZ + col);
      uint4 pkA;
      pkA.x = f2bf(c0[0]) | (f2bf(c1[0]) << 16);
      pkA.y = f2bf(c2[0]) | (f2bf(c3[0]) << 16);
      pkA.z = f2bf(c0[1]) | (f2bf(c1[1]) << 16);
      pkA.w = f2bf(c2[1]) | (f2bf(c3[1]) << 16);
      *(uint4*)&xqA[col * 2] = pkA;
      f32x2v c4 = *(const f32x2v*)(s0 + 4 * HWSZ + col);
      f32x2v c5 = *(const f32x2v*)(s0 + 5 * HWSZ + col);
      f32x2v c6 = *(const f32x2v*)(s0 + 6 * HWSZ + col);
      f32x2v c7 = *(const f32x2v*)(s0 + 7 * HWSZ + col);
      uint4 pkB;
      pkB.x = f2bf(c4[0]) | (f2bf(c5[0]) << 16);
      pkB.y = f2bf(c6[0]) | (f2bf(c7[0]) << 16);
      pkB.z = f2bf(c4[1]) | (f2bf(c5[1]) << 16);
      pkB.w = f2bf(c6[1]) | (f2bf(c7[1]) << 16);
      *(uint4*)&xqB[col * 2] = pkB;
    }
  }
  __syncthreads();

  for (int it = 0; it < 5; ++it) {
    if (it == 4 && tid >= 256) break;          // no barriers below; safe
    const int n = n0 + it * 512 + tid;
    uint_t ofr[9]; float4 wtr[9];
#pragma unroll
    for (int k = 0; k < 9; ++k) {
      ofr[k] = offs[(size_t)k * NPIX + n];
      wtr[k] = wts[(size_t)k * NPIX + n];
    }
    uint_t pkw[36];
#pragma unroll
    for (int i = 0; i < 36; ++i) pkw[i] = 0u;
#pragma unroll
    for (int k = 0; k < 9; ++k) {
      const int o0 = (int)(ofr[k] & 0xffffu);
      const int o1 = (int)(ofr[k] >> 16);
      const float4 wv = wtr[k];
      uint2 A00 = *(const uint2*)&xqA[o0 * 2];
      uint2 A01 = *(const uint2*)&xqA[o0 * 2 + 2];
      uint2 A10 = *(const uint2*)&xqA[o1 * 2];
      uint2 A11 = *(const uint2*)&xqA[o1 * 2 + 2];
      uint2 B00 = *(const uint2*)&xqB[o0 * 2];
      uint2 B01 = *(const uint2*)&xqB[o0 * 2 + 2];
      uint2 B10 = *(const uint2*)&xqB[o1 * 2];
      uint2 B11 = *(const uint2*)&xqB[o1 * 2 + 2];
      float v[8];
      v[0] = wv.x * bflo(A00.x) + wv.y * bflo(A01.x) + wv.z * bflo(A10.x) + wv.w * bflo(A11.x);
      v[1] = wv.x * bfhi(A00.x) + wv.y * bfhi(A01.x) + wv.z * bfhi(A10.x) + wv.w * bfhi(A11.x);
      v[2] = wv.x * bflo(A00.y) + wv.y * bflo(A01.y) + wv.z * bflo(A10.y) + wv.w * bflo(A11.y);
      v[3] = wv.x * bfhi(A00.y) + wv.y * bfhi(A01.y) + wv.z * bfhi(A10.y) + wv.w * bfhi(A11.y);
      v[4] = wv.x * bflo(B00.x) + wv.y * bflo(B01.x) + wv.z * bflo(B10.x) + wv.w * bflo(B11.x);
      v[5] = wv.x * bfhi(B00.x) + wv.y * bfhi(B01.x) + wv.z * bfhi(B10.x) + wv.w * bfhi(B11.x);
      v[6] = wv.x * bflo(B00.y) + wv.y * bflo(B01.y) + wv.z * bflo(B10.y) + wv.w * bflo(B11.y);
      v[7] = wv.x * bfhi(B00.y) + wv.y * bfhi(B01.y) + wv.z * bfhi(B10.y) + wv.w * bfhi(B11.y);
#pragma unroll
      for (int c = 0; c < 8; ++c) {
        const int q = c * 9 + k;               // static
        pkw[q >> 1] |= f2bf(v[c]) << ((q & 1) * 16);
      }
    }
#pragma unroll
    for (int g = 0; g < 9; ++g) {
      uint4 st = make_uint4(pkw[4 * g], pkw[4 * g + 1], pkw[4 * g + 2], pkw[4 * g + 3]);
      *(uint4*)&S_g[((size_t)(9 * by + g) * NPIX + n) * 8] = st;
    }
  }
}

// ---------------- s_gemm: out = W9 * S + b_dcn ; BN partials fused ----------------
// BM=128 (blockIdx.y half), BN=64, BK=32, 72 chunks, grid (288,2) = 576.
// 4-slot ring 48KB -> 2.25 blocks/CU resident. Wave tile 32x32.
__global__ __launch_bounds__(512, 2) void s_gemm(
    const ushort_t* __restrict__ w9r, const ushort_t* __restrict__ S_g,
    const float* __restrict__ b_dcn, float* __restrict__ out,
    float2* __restrict__ bnp2) {
  __shared__ __align__(16) ushort_t A[4][4096];   // [slot][kg][128][8] = 32 KB
  __shared__ __align__(16) ushort_t S[4][2048];   // [slot][kg][64][8]  = 16 KB

  const int tid = threadIdx.x;
  const int lane = tid & 63, wid = tid >> 6;
  const int p0 = blockIdx.x * 64;              // 288 n-tiles
  const int m0 = blockIdx.y * 128;             // channel half
  const int bimg = p0 / HWSZ;
  const int hw0 = p0 - bimg * HWSZ;
  const int lg = lane >> 4, lm = lane & 15;
  const int wr = wid >> 1, wc = wid & 1;       // wave tile rows wr*32, cols wc*32
  const int sg = tid >> 7, sp = tid & 127;     // A stage: kgroup, row

  f32x4 acc[2][2];
#pragma unroll
  for (int i = 0; i < 2; ++i)
#pragma unroll
    for (int j = 0; j < 2; ++j) acc[i][j] = (f32x4){0.f, 0.f, 0.f, 0.f};

#define SG_STAGE(CH, BUF)                                                     \
  {                                                                           \
    gload16(w9r + ((size_t)((CH) * 4 + sg) * 256 + m0 + sp) * 8,              \
            &A[BUF][(sg * 128 + sp) * 8]);                                    \
    if (wid < 4)                                                              \
      gload16(S_g + ((size_t)((CH) * 4 + wid) * NPIX + p0 + lane) * 8,        \
              &S[BUF][(wid * 64 + lane) * 8]);                                \
  }
#define SG_MFMA(BUF)                                                         \
  {                                                                          \
    bf16x8 af0 = *(const bf16x8*)&A[BUF][(lg * 128 + wr * 32 + lm) * 8];     \
    bf16x8 af1 = *(const bf16x8*)&A[BUF][(lg * 128 + wr * 32 + 16 + lm) * 8];\
    _Pragma("unroll") for (int ni = 0; ni < 2; ++ni) {                       \
      bf16x8 bfv = *(const bf16x8*)&S[BUF][(lg * 64 + wc * 32 + ni * 16 + lm) * 8]; \
      acc[0][ni] = __builtin_amdgcn_mfma_f32_16x16x32_bf16(af0, bfv, acc[0][ni], 0, 0, 0); \
      acc[1][ni] = __builtin_amdgcn_mfma_f32_16x16x32_bf16(af1, bfv, acc[1][ni], 0, 0, 0); \
    }                                                                        \
  }

  SG_STAGE(0, 0)
  SG_STAGE(1, 1)
  for (int ko = 0; ko < 72; ++ko) {
    if (ko < 70) {
      SG_STAGE(ko + 2, (ko + 2) & 3)
      if (wid < 4) { asm volatile("s_waitcnt vmcnt(4)" ::: "memory"); }
      else         { asm volatile("s_waitcnt vmcnt(2)" ::: "memory"); }
    } else if (ko == 70) {
      if (wid < 4) { asm volatile("s_waitcnt vmcnt(2)" ::: "memory"); }
      else         { asm volatile("s_waitcnt vmcnt(1)" ::: "memory"); }
    } else {
      asm volatile("s_waitcnt vmcnt(0)" ::: "memory");
    }
    __builtin_amdgcn_s_barrier();
    __builtin_amdgcn_sched_barrier(0);
    SG_MFMA(ko & 3)
  }
#undef SG_STAGE
#undef SG_MFMA

  // ---- epilogue: store out + BN partial stats ----
  float bsum[8], bsq[8];
#pragma unroll
  for (int mi = 0; mi < 2; ++mi) {
#pragma unroll
    for (int r = 0; r < 4; ++r) {
      int o = m0 + wr * 32 + mi * 16 + lg * 4 + r;
      float b = b_dcn[o];
      float s = 0.f, q = 0.f;
#pragma unroll
      for (int ni = 0; ni < 2; ++ni) {
        float v = acc[mi][ni][r] + b;
        out[((size_t)(bimg * CO + o)) * HWSZ + hw0 + wc * 32 + ni * 16 + lm] = v;
        s += v; q += v * v;
      }
      bsum[mi * 4 + r] = s;
      bsq[mi * 4 + r] = q;
    }
  }
#pragma unroll
  for (int d = 1; d < 16; d <<= 1) {
#pragma unroll
    for (int i = 0; i < 8; ++i) {
      bsum[i] += __shfl_xor(bsum[i], d);
      bsq[i] += __shfl_xor(bsq[i], d);
    }
  }
  asm volatile("s_waitcnt lgkmcnt(0)" ::: "memory");
  __builtin_amdgcn_s_barrier();                 // all LDS reads done -> reuse A
  float* red = (float*)&A[0][0];                // 512 floats
  if (lm == 0) {
#pragma unroll
    for (int i = 0; i < 8; ++i) {
      int ol = wr * 32 + (i >> 2) * 16 + lg * 4 + (i & 3);   // 0..127
      red[ol * 2 + wc] = bsum[i];
      red[256 + ol * 2 + wc] = bsq[i];
    }
  }
  __syncthreads();
  if (tid < 128) {
    float s = red[tid * 2] + red[tid * 2 + 1];
    float q = red[256 + tid * 2] + red[256 + tid * 2 + 1];
    bnp2[(size_t)(m0 + tid) * 288 + blockIdx.x] = make_float2(s, q);
  }
}

// ---------------- BN finalize: 256 blocks x 64 thr ----------------
__global__ __launch_bounds__(64) void bn_finl(const float2* __restrict__ bnp2,
                                              const float* __restrict__ gamma,
                                              const float* __restrict__ beta,
                                              float* __restrict__ ss) {
  int o = blockIdx.x, t = threadIdx.x;
  float s = 0.f, q = 0.f;
  for (int j = t; j < 288; j += 64) {
    float2 p = bnp2[(size_t)o * 288 + j];
    s += p.x; q += p.y;
  }
#pragma unroll
  for (int d = 32; d > 0; d >>= 1) {
    s += __shfl_xor(s, d);
    q += __shfl_xor(q, d);
  }
  if (t == 0) {
    float mean = s * (1.f / (float)NPIX);
    float var = q * (1.f / (float)NPIX) - mean * mean;
    float rstd = rsqrtf(var + 1e-5f);
    float sc = rstd * gamma[o];
    ss[o] = sc;
    ss[CO + o] = beta[o] - mean * sc;
  }
}

// ---------------- BN apply + ReLU ----------------
__global__ void bn_apply(float* __restrict__ out, const float* __restrict__ ss) {
  int i = blockIdx.x * 256 + threadIdx.x;
  float4 v = ((float4*)out)[i];
  int o = (i / (HWSZ / 4)) & 255;
  float sc = ss[o], sh = ss[CO + o];
  v.x = fmaxf(v.x * sc + sh, 0.f);
  v.y = fmaxf(v.y * sc + sh, 0.f);
  v.z = fmaxf(v.z * sc + sh, 0.f);
  v.w = fmaxf(v.w * sc + sh, 0.f);
  ((float4*)out)[i] = v;
}

extern "C" void kernel_launch(void* const* d_in, const int* in_sizes, int n_in,
                              void* d_out, int out_size, void* d_ws, size_t ws_size,
                              hipStream_t stream) {
  const float* x = (const float*)d_in[0];
  const float* w_off = (const float*)d_in[1];
  const float* b_off = (const float*)d_in[2];
  const float* w_dcn = (const float*)d_in[3];
  const float* b_dcn = (const float*)d_in[4];
  const float* gamma = (const float*)d_in[5];
  const float* beta = (const float*)d_in[6];
  float* out = (float*)d_out;

  char* ws = (char*)d_ws;

  size_t base = 84934656;                      // S_g occupies [0, base)
  ushort_t* S_g   = (ushort_t*)(ws);
  float*    om    = (float*)(ws + base);                    // 2*27*NPIX*4 = 3,981,312
  float2*   bnp2  = (float2*)(ws + base);                   // aliases om (dead after prep)
  uint_t*   offs  = (uint_t*)(ws + base + 3981312);         //   663,552
  float4*   wts   = (float4*)(ws + base + 4644864);         // 2,654,208
  ushort_t* w9r   = (ushort_t*)(ws + base + 7299072);       // 1,179,648
  ushort_t* w27r  = (ushort_t*)(ws + base + 8478720);       //   147,456
  float*    ss    = (float*)(ws + base + 8626176);          //     2,048

  cvt_w9<<<(CO * KTOT) / 256, 256, 0, stream>>>(w_dcn, w9r);
  cvt_woff9<<<(32 * KTOT) / 256, 256, 0, stream>>>(w_off, w27r);
  off_gemm<<<dim3(NPIX / 64, 2), 512, 0, stream>>>(x, w27r, om);
  prep_kernel<<<NPIX / 128, 128, 0, stream>>>(om, b_off, offs, wts);
  sample8<<<dim3(8, 32), 512, 0, stream>>>(x, offs, wts, S_g);
  s_gemm<<<dim3(NPIX / 64, 2), 512, 0, stream>>>(w9r, S_g, b_dcn, out, bnp2);
  bn_finl<<<CO, 64, 0, stream>>>(bnp2, gamma, beta, ss);
  bn_apply<<<(out_size / 4) / 256, 256, 0, stream>>>(out, ss);
}